// Round 8
// baseline (335.239 us; speedup 1.0000x reference)
//
#include <hip/hip_runtime.h>
#include <hip/hip_bf16.h>

using bf16 = __hip_bfloat16;

typedef float floatx4 __attribute__((ext_vector_type(4)));
typedef short shortx8 __attribute__((ext_vector_type(8)));
typedef short shortx4 __attribute__((ext_vector_type(4)));
typedef __bf16 bf16x8 __attribute__((ext_vector_type(8)));

#define NEG_BIG -3.0e38f

// async global->LDS DMA, 16 B per lane; LDS dest = wave-uniform base + lane*16
#define GLOAD_LDS16(g, l)                                                     \
  __builtin_amdgcn_global_load_lds(                                           \
      (const __attribute__((address_space(1))) unsigned int*)(g),             \
      (__attribute__((address_space(3))) unsigned int*)(l), 16, 0, 0)

__device__ __forceinline__ float bf2f(short s) {
  union { unsigned int u; float f; } x;
  x.u = ((unsigned int)(unsigned short)s) << 16;
  return x.f;
}

// ---------------- dtype sniff: cos[0]==1.0 exactly.
// fp32 -> word0 = 0x3F800000 ; bf16 -> word0 = 0x3F803F80 (two packed 1.0's)
__global__ void sniff_k(const void* __restrict__ cosp, int* __restrict__ flag) {
  unsigned w = *(const unsigned*)cosp;
  *flag = (w == 0x3F800000u) ? 1 : 0;  // 1 = inputs are fp32
}

// ---------------- generic input -> bf16 convert, vectorized x8 ----------------
__global__ void conv_k(const void* __restrict__ src, bf16* __restrict__ dst, int n8,
                       const int* __restrict__ flag) {
  int i = blockIdx.x * blockDim.x + threadIdx.x;
  if (i >= n8) return;
  shortx8 r;
  if (*flag) {
    const float4* s4 = (const float4*)src;
    float4 x0 = s4[i * 2], x1 = s4[i * 2 + 1];
    float xs[8] = {x0.x, x0.y, x0.z, x0.w, x1.x, x1.y, x1.z, x1.w};
#pragma unroll
    for (int e = 0; e < 8; ++e)
      r[e] = (short)__bfloat16_as_ushort(__float2bfloat16(xs[e]));
  } else {
    r = ((const shortx8*)src)[i];
  }
  *(shortx8*)(dst + (size_t)i * 8) = r;
}

// ---------------- 6-way fused convert+transpose: src (2048, C) -> dst (C, 2048) ------
// z selects {wq, wk, wv, wo, cos, sin}; oversized x-blocks early-exit. Replaces 6
// separate launches (R7 post-mortem: ~12 graph nodes, gaps + tiny kernels ~15% of wall).
struct Trans6 {
  const void* src[6];
  bf16* dst[6];
  int C[6];
};
__global__ void trans6_k(Trans6 td, const int* __restrict__ flag) {
  const int z = blockIdx.z;
  const int C = td.C[z];
  if ((int)blockIdx.x * 32 >= C) return;
  __shared__ bf16 tile[32][33];
  const void* src = td.src[z];
  bf16* dst = td.dst[z];
  int fp32 = *flag;
  int tx = threadIdx.x, ty = threadIdx.y;
  int c0 = blockIdx.x * 32, r0 = blockIdx.y * 32;
#pragma unroll
  for (int i = 0; i < 32; i += 8) {
    size_t idx = (size_t)(r0 + ty + i) * C + c0 + tx;
    tile[ty + i][tx] = fp32 ? __float2bfloat16(((const float*)src)[idx])
                            : ((const bf16*)src)[idx];
  }
  __syncthreads();
#pragma unroll
  for (int i = 0; i < 32; i += 8)
    dst[(size_t)(c0 + ty + i) * 2048 + r0 + tx] = tile[tx][ty + i];
}

// ---------------- GEMM BMx256 ring kernel; EPI=1 fuses RoPE + V-transpose -------------
// Structure (R6/R7, verified): 8 waves, 4-deep LDS ring of K=32 tiles, depth-2
// prefetch via global_load_lds, ONE raw s_barrier + counted vmcnt per K-tile (T4).
// T2-lite source-side swizzle; T1 XCD swizzle (grids % 8 == 0).
// EPI=1 (QKV projection): per-block-uniform epilogue on n0:
//   n0 <  2560 (q/k heads): RoPE on fp32 acc. Partner (ncol^32) is IN-LANE
//     (acc[r][c^2], same i); sign −sin for c<2 (d<32), +sin else. cos/sin read from
//     TRANSPOSED tables cosT/sinT[d][p] so 4 rows = one shortx4. q heads (n0<2048)
//     also fold the exact 0.125 softmax pre-scale here (attn no longer scales Q).
//     Store bf16 to qkv with LDC=2560 (V moved out of qkv).
//   n0 >= 2560 (v heads): write DIRECTLY transposed to Vt[(b*8+kvh)*64+d][kv] —
//     acc[r][c][0..3] are consecutive kv -> one shortx4 store. Replaces vt_k.
template<int BM, int EPI>
__global__ __launch_bounds__(512) void gemm256(const bf16* __restrict__ A,
                                               const bf16* __restrict__ Bt,
                                               void* __restrict__ Cp,
                                               bf16* __restrict__ Vt,
                                               const bf16* __restrict__ cosT,
                                               const bf16* __restrict__ sinT,
                                               int M, int N, int K,
                                               const int* __restrict__ flag,
                                               int f32out_en) {
  constexpr int NR = BM / 32;          // row frags per wave: 8 or 4
  constexpr int ABASE = BM * 32;       // A region shorts
  constexpr int BUFS = ABASE + 8192;   // + B region (256x32 shorts)
  __shared__ __align__(16) short lds[4][BUFS];
  const int f32out = (EPI == 0 && f32out_en) ? *flag : 0;
  const int tid = threadIdx.x;
  const int w = tid >> 6, lane = tid & 63;
  const int wr = w >> 2, wc = w & 3;
  const int quad = lane >> 4, l15 = lane & 15;

  // XCD-aware bijective swizzle (nwg % 8 == 0 for all launches)
  const int nwg = gridDim.x;
  const int id = blockIdx.x;
  const int swz = (id & 7) * (nwg >> 3) + (id >> 3);
  const int nbx = N >> 8;
  const int bx = swz % nbx, by = swz / nbx;
  const int m0 = by * BM, n0 = bx << 8;

  // staging source (inverse-swizzled): lane covers row rl, 16B slot (lane&3)^(rl&3)
  const int rl = lane >> 2;
  const int c8 = (((lane & 3) ^ (rl & 3)) << 3);
  const bf16 *gA0, *gA1;
  if constexpr (BM == 256) {
    gA0 = A + (size_t)(m0 + w * 32 + rl) * K + c8;
    gA1 = gA0 + (size_t)16 * K;
  } else {
    gA0 = A + (size_t)(m0 + w * 16 + rl) * K + c8;
    gA1 = gA0;  // unused
  }
  const bf16* gB0 = Bt + (size_t)(n0 + w * 32 + rl) * K + c8;
  const bf16* gB1 = gB0 + (size_t)16 * K;

  floatx4 acc[NR][4];
#pragma unroll
  for (int r = 0; r < NR; ++r)
#pragma unroll
    for (int c = 0; c < 4; ++c)
      acc[r][c] = (floatx4){0.f, 0.f, 0.f, 0.f};

  // swizzled ds_read offsets (shorts); frag row & 3 == l15 & 3
  const int xr = (quad * 8) ^ ((l15 & 3) << 3);
  const int aoff = (wr * (BM / 2) + l15) * 32 + xr;
  const int boff = ABASE + (wc * 64 + l15) * 32 + xr;

  const int nkt = K >> 5;

  auto STAGE = [&](int tt) {
    short* d_ = &lds[tt & 3][0];
    const int k0_ = tt << 5;
    if constexpr (BM == 256) {
      GLOAD_LDS16(gA0 + k0_, d_ + (w << 10));
      GLOAD_LDS16(gA1 + k0_, d_ + (w << 10) + 512);
    } else {
      GLOAD_LDS16(gA0 + k0_, d_ + (w << 9));
    }
    GLOAD_LDS16(gB0 + k0_, d_ + ABASE + (w << 10));
    GLOAD_LDS16(gB1 + k0_, d_ + ABASE + (w << 10) + 512);
  };

  STAGE(0);
  STAGE(1);

  for (int t = 0; t < nkt; ++t) {
    if (t + 2 < nkt) {
      STAGE(t + 2);
      if constexpr (BM == 256) asm volatile("s_waitcnt vmcnt(8)" ::: "memory");
      else                     asm volatile("s_waitcnt vmcnt(6)" ::: "memory");
    } else if (t + 1 < nkt) {
      if constexpr (BM == 256) asm volatile("s_waitcnt vmcnt(4)" ::: "memory");
      else                     asm volatile("s_waitcnt vmcnt(3)" ::: "memory");
    } else {
      asm volatile("s_waitcnt vmcnt(0)" ::: "memory");
    }
    __builtin_amdgcn_s_barrier();
    __builtin_amdgcn_sched_barrier(0);  // keep ds_reads below the barrier

    const short* bufS = &lds[t & 3][0];
    bf16x8 af[NR], bfr[4];
#pragma unroll
    for (int r = 0; r < NR; ++r)
      af[r] = __builtin_bit_cast(bf16x8, *(const shortx8*)(bufS + aoff + r * 512));
#pragma unroll
    for (int c = 0; c < 4; ++c)
      bfr[c] = __builtin_bit_cast(bf16x8, *(const shortx8*)(bufS + boff + c * 512));
#pragma unroll
    for (int r = 0; r < NR; ++r)
#pragma unroll
      for (int c = 0; c < 4; ++c)
        acc[r][c] = __builtin_amdgcn_mfma_f32_16x16x32_bf16(af[r], bfr[c], acc[r][c], 0, 0, 0);
  }

  if constexpr (EPI == 1) {
    if (n0 >= 2560) {
      // ---- V columns: store transposed into Vt ----
#pragma unroll
      for (int r = 0; r < NR; ++r) {
#pragma unroll
        for (int c = 0; c < 4; ++c) {
          int dg = n0 + wc * 64 + c * 16 + l15 - 2560;   // 0..511
          int kvh = dg >> 6, dd = dg & 63;
          int mrow = m0 + wr * (BM / 2) + r * 16 + quad * 4;
          int bb = mrow >> 11, kv = mrow & 2047;
          shortx4 o4;
#pragma unroll
          for (int i = 0; i < 4; ++i)
            o4[i] = (short)__bfloat16_as_ushort(__float2bfloat16(acc[r][c][i]));
          *(shortx4*)(Vt + ((size_t)(bb * 8 + kvh) * 64 + dd) * 2048 + kv) = o4;
        }
      }
    } else {
      // ---- q/k columns: RoPE on fp32 acc, q additionally scaled by 0.125 ----
      const float qsc = (n0 < 2048) ? 0.125f : 1.0f;
#pragma unroll
      for (int r = 0; r < NR; ++r) {
        int mrow = m0 + wr * (BM / 2) + r * 16 + quad * 4;
        int pp = mrow & 2047;
#pragma unroll
        for (int c = 0; c < 4; ++c) {
          int ncol = n0 + wc * 64 + c * 16 + l15;
          int dd = ncol & 63;
          shortx4 cs = *(const shortx4*)(cosT + (size_t)dd * 2048 + pp);
          shortx4 sn = *(const shortx4*)(sinT + (size_t)dd * 2048 + pp);
          float sgn = (c & 2) ? 1.f : -1.f;   // d>=32: +sin*partner(d-32); d<32: -sin*partner(d+32)
#pragma unroll
          for (int i = 0; i < 4; ++i) {
            float a = acc[r][c][i];
            float bp = acc[r][c ^ 2][i];
            float outv = (a * bf2f(cs[i]) + sgn * bp * bf2f(sn[i])) * qsc;
            ((bf16*)Cp)[(size_t)(mrow + i) * 2560 + ncol] = __float2bfloat16(outv);
          }
        }
      }
    }
  } else {
#pragma unroll
    for (int r = 0; r < NR; ++r) {
#pragma unroll
      for (int c = 0; c < 4; ++c) {
        int mrow = m0 + wr * (BM / 2) + r * 16 + quad * 4;
        int ncol = n0 + wc * 64 + c * 16 + l15;
        if (f32out) {
#pragma unroll
          for (int i = 0; i < 4; ++i)
            ((float*)Cp)[(size_t)(mrow + i) * N + ncol] = acc[r][c][i];
        } else {
#pragma unroll
          for (int i = 0; i < 4; ++i)
            ((bf16*)Cp)[(size_t)(mrow + i) * N + ncol] = __float2bfloat16(acc[r][c][i]);
        }
      }
    }
  }
}

// ---------------- flash attention (causal, GQA 4:1) — swapped-QK^T, 64-row q-tiles ---
// R7 post-mortem: 512 blocks = 2 blocks/CU, occupancy 19%, 39% idle. Split q-tile
// 128 -> 64 rows: grid (16,32,2) = 1024 UNIFORM blocks (pair qt=p with 31-p => 33
// kv-iters each — the R2-safe balancing), 4 blocks/CU, 16 waves/CU. Per-wave state
// halves (16 q-rows). Q is pre-scaled 0.125 in the QKV-gemm epilogue now.
// Swapped S^T = mfma(K,Q): lane holds S[kv=nb*16+quad*4+i][q=l15]; softmax in-reg
// (15 fmax + 2 shfl); P feeds PV A-frag directly (sigma-matched V b64 reads).
// T13 defer-rescale (thr 8); T5 setprio around both MFMA clusters (R7: +3%).
__global__ __launch_bounds__(256) void attn_k(const bf16* __restrict__ qkv,
                                              const bf16* __restrict__ Vt,
                                              bf16* __restrict__ O) {
  const int S = 2048, LDQ = 2560, D = 2048;
  const int p = blockIdx.x, h = blockIdx.y, b = blockIdx.z;
  const int kvh = h >> 2;
  const int tid = threadIdx.x;
  const int w = tid >> 6, lane = tid & 63;
  const int quad = lane >> 4, l15 = lane & 15;

  __shared__ __align__(16) short sK [2][64][72];  // [buf][kv pos][hd]
  __shared__ __align__(16) short sVt[2][64][72];  // [buf][hd][kv pos]

  const int srow = tid >> 2, sseg = (tid & 3) * 16;
  const bf16* kbase = qkv + (size_t)(b * S) * LDQ + 2048 + kvh * 64 + sseg;       // row=kv
  const bf16* vbase = Vt + ((size_t)(b * 8 + kvh) * 64 + srow) * 2048 + sseg;     // row=d

  for (int phase = 0; phase < 2; ++phase) {
    const int qt = phase ? (31 - p) : p;
    const int q0 = qt * 64;

    // Q fragments (pre-scaled in gemm epilogue): 16 rows/wave, 2 k-halves
    bf16x8 qa[2];
    {
      const bf16* qp = qkv + (size_t)(b * S + q0 + w * 16 + l15) * LDQ + h * 64 + quad * 8;
      qa[0] = __builtin_bit_cast(bf16x8, *(const shortx8*)qp);
      qa[1] = __builtin_bit_cast(bf16x8, *(const shortx8*)(qp + 32));
    }

    floatx4 oacc[4];
#pragma unroll
    for (int d = 0; d < 4; ++d) oacc[d] = (floatx4){0.f, 0.f, 0.f, 0.f};
    float m_i = NEG_BIG, l_p = 0.f;

    const int jtEnd = qt + 1;

    // stage tile 0 into buf 0
    {
      const bf16* kp = kbase + (size_t)srow * LDQ;
      *(int4*)&sK [0][srow][sseg]     = *(const int4*)kp;
      *(int4*)&sK [0][srow][sseg + 8] = *(const int4*)(kp + 8);
      *(int4*)&sVt[0][srow][sseg]     = *(const int4*)vbase;
      *(int4*)&sVt[0][srow][sseg + 8] = *(const int4*)(vbase + 8);
    }
    __syncthreads();

    int cur = 0;
    for (int jt = 0; jt < jtEnd; ++jt) {
      // ---- prefetch next tile into regs (latency hides under compute) ----
      int4 kr0, kr1, vr0, vr1;
      const bool pre = (jt + 1 < jtEnd);
      if (pre) {
        const bf16* kp2 = kbase + (size_t)((jt + 1) * 64 + srow) * LDQ;
        kr0 = *(const int4*)kp2;
        kr1 = *(const int4*)(kp2 + 8);
        const bf16* vp2 = vbase + (jt + 1) * 64;
        vr0 = *(const int4*)vp2;
        vr1 = *(const int4*)(vp2 + 8);
      }

      // ---- S^T = K Q^T ----
      floatx4 sfr[4];
#pragma unroll
      for (int nb = 0; nb < 4; ++nb) sfr[nb] = (floatx4){0.f, 0.f, 0.f, 0.f};
      __builtin_amdgcn_s_setprio(1);
#pragma unroll
      for (int kk = 0; kk < 2; ++kk) {
#pragma unroll
        for (int nb = 0; nb < 4; ++nb) {
          bf16x8 kf = __builtin_bit_cast(bf16x8,
              *(const shortx8*)&sK[cur][nb * 16 + l15][kk * 32 + quad * 8]);
          sfr[nb] = __builtin_amdgcn_mfma_f32_16x16x32_bf16(kf, qa[kk], sfr[nb], 0, 0, 0);
        }
      }
      __builtin_amdgcn_s_setprio(0);

      // ---- mask (diagonal tile only), in-lane row softmax with T13 defer ----
      if (jt == qt) {
        const int rg = q0 + w * 16 + l15;
#pragma unroll
        for (int nb = 0; nb < 4; ++nb)
#pragma unroll
          for (int i = 0; i < 4; ++i) {
            int jg = jt * 64 + nb * 16 + quad * 4 + i;
            if (jg > rg) sfr[nb][i] = NEG_BIG;
          }
      }
      float m = fmaxf(fmaxf(sfr[0][0], sfr[0][1]), fmaxf(sfr[0][2], sfr[0][3]));
#pragma unroll
      for (int nb = 1; nb < 4; ++nb)
#pragma unroll
        for (int i = 0; i < 4; ++i) m = fmaxf(m, sfr[nb][i]);
      m = fmaxf(m, __shfl_xor(m, 16));
      m = fmaxf(m, __shfl_xor(m, 32));

      bool grow = m > m_i + 8.f;
      if (__any((int)grow)) {
        float Mn = fmaxf(m_i, m);
        float alpha = __expf(m_i - Mn);
        m_i = Mn;
        l_p *= alpha;
#pragma unroll
        for (int i = 0; i < 4; ++i) {
          float ai = __shfl(alpha, (lane & 48) | (quad * 4 + i));
#pragma unroll
          for (int d = 0; d < 4; ++d) oacc[d][i] *= ai;
        }
      }
      float rs = 0.f;
#pragma unroll
      for (int nb = 0; nb < 4; ++nb)
#pragma unroll
        for (int i = 0; i < 4; ++i) {
          float pv = __expf(sfr[nb][i] - m_i);
          sfr[nb][i] = pv;
          rs += pv;
        }
      l_p += rs;

      // ---- O += P V: P in-register A-frags (sigma-permuted), V via 2x ds_read_b64 ----
      __builtin_amdgcn_s_setprio(1);
#pragma unroll
      for (int kk = 0; kk < 2; ++kk) {
        bf16x8 pf;
#pragma unroll
        for (int e = 0; e < 4; ++e) {
          pf[e]     = (__bf16)sfr[2 * kk][e];
          pf[e + 4] = (__bf16)sfr[2 * kk + 1][e];
        }
#pragma unroll
        for (int db = 0; db < 4; ++db) {
          const short* vrow = &sVt[cur][db * 16 + l15][0];
          shortx4 va = *(const shortx4*)(vrow + kk * 32 + quad * 4);
          shortx4 vb = *(const shortx4*)(vrow + kk * 32 + 16 + quad * 4);
          bf16x8 vf = __builtin_bit_cast(bf16x8,
              __builtin_shufflevector(va, vb, 0, 1, 2, 3, 4, 5, 6, 7));
          oacc[db] = __builtin_amdgcn_mfma_f32_16x16x32_bf16(pf, vf, oacc[db], 0, 0, 0);
        }
      }
      __builtin_amdgcn_s_setprio(0);

      // ---- write prefetched tile into the other buffer; single barrier ----
      if (pre) {
        *(int4*)&sK [cur ^ 1][srow][sseg]     = kr0;
        *(int4*)&sK [cur ^ 1][srow][sseg + 8] = kr1;
        *(int4*)&sVt[cur ^ 1][srow][sseg]     = vr0;
        *(int4*)&sVt[cur ^ 1][srow][sseg + 8] = vr1;
      }
      __syncthreads();
      cur ^= 1;
    }

    // ---- epilogue: cross-quad l reduce, shfl per O-row, store ----
    {
      float l = l_p;
      l += __shfl_xor(l, 16);
      l += __shfl_xor(l, 32);
      float inv = 1.f / l;
#pragma unroll
      for (int i = 0; i < 4; ++i) {
        float ii = __shfl(inv, (lane & 48) | (quad * 4 + i));
        bf16* op = O + (size_t)(b * S + q0 + w * 16 + quad * 4 + i) * D + h * 64 + l15;
#pragma unroll
        for (int db = 0; db < 4; ++db)
          op[db * 16] = __float2bfloat16(oacc[db][i] * ii);
      }
    }
  }
}

// ---------------- launch ----------------
// ws layout (bf16 elements from ws16 = d_ws + 16; flag int at d_ws):
//   xb 8.4M | cosT 131k | sinT 131k | bt_qkv 6.3M | wot 4.2M | qkv(2560-wide) 10.5M |
//   vt 2.1M  (~63.3 MB). o reuses xb (x dead after QKV GEMM).
// 6 launches total (was 12): sniff, conv(x), trans6, gemmQKV(RoPE+Vt fused), attn,
// gemmOUT.
extern "C" void kernel_launch(void* const* d_in, const int* in_sizes, int n_in,
                              void* d_out, int out_size, void* d_ws, size_t ws_size,
                              hipStream_t stream) {
  const void* x    = d_in[0];
  const void* cosp = d_in[1];
  const void* sinp = d_in[2];
  const void* wq   = d_in[3];
  const void* wk   = d_in[4];
  const void* wv   = d_in[5];
  const void* wo   = d_in[6];

  int* flag = (int*)d_ws;
  bf16* ws16 = (bf16*)((char*)d_ws + 16);
  bf16* xb     = ws16;
  bf16* cosT   = xb + (size_t)8388608;
  bf16* sinT   = cosT + 131072;
  bf16* bt_qkv = sinT + 131072;
  bf16* wot    = bt_qkv + (size_t)3072 * 2048;
  bf16* qkv    = wot + (size_t)2048 * 2048;          // 4096 x 2560 (q+k only)
  bf16* vt     = qkv + (size_t)4096 * 2560;          // [2*8*64][2048]
  bf16* o      = xb;  // x dead after QKV GEMM; attn output reuses it

  sniff_k<<<1, 1, 0, stream>>>(cosp, flag);

  conv_k<<<(1048576 + 255) / 256, 256, 0, stream>>>(x, xb, 1048576, flag);

  Trans6 td;
  td.src[0] = wq;   td.dst[0] = bt_qkv;                         td.C[0] = 2048;
  td.src[1] = wk;   td.dst[1] = bt_qkv + (size_t)2048 * 2048;   td.C[1] = 512;
  td.src[2] = wv;   td.dst[2] = bt_qkv + (size_t)2560 * 2048;   td.C[2] = 512;
  td.src[3] = wo;   td.dst[3] = wot;                            td.C[3] = 2048;
  td.src[4] = cosp; td.dst[4] = cosT;                           td.C[4] = 64;
  td.src[5] = sinp; td.dst[5] = sinT;                           td.C[5] = 64;
  trans6_k<<<dim3(64, 64, 6), dim3(32, 8), 0, stream>>>(td, flag);

  // QKV projection + fused RoPE (q scaled 0.125) + fused V-transpose
  gemm256<256, 1><<<dim3(192), 512, 0, stream>>>(xb, bt_qkv, qkv, vt, cosT, sinT,
                                                 4096, 3072, 2048, flag, 0);

  // attention: 1024 uniform blocks (qt pair p / 31-p), 64-row q-tiles, 4 blocks/CU
  attn_k<<<dim3(16, 32, 2), 256, 0, stream>>>(qkv, vt, o);

  // output projection: BM=128, 256 blocks (100% util); dtype follows input
  gemm256<128, 0><<<dim3(256), 512, 0, stream>>>(o, wot, d_out, nullptr, nullptr, nullptr,
                                                 4096, 2048, 2048, flag, 1);
}

// Round 9
// 326.802 us; speedup vs baseline: 1.0258x; 1.0258x over previous
//
#include <hip/hip_runtime.h>
#include <hip/hip_bf16.h>

using bf16 = __hip_bfloat16;

typedef float floatx4 __attribute__((ext_vector_type(4)));
typedef short shortx8 __attribute__((ext_vector_type(8)));
typedef short shortx4 __attribute__((ext_vector_type(4)));
typedef __bf16 bf16x8 __attribute__((ext_vector_type(8)));

#define NEG_BIG -3.0e38f

// async global->LDS DMA, 16 B per lane; LDS dest = wave-uniform base + lane*16
#define GLOAD_LDS16(g, l)                                                     \
  __builtin_amdgcn_global_load_lds(                                           \
      (const __attribute__((address_space(1))) unsigned int*)(g),             \
      (__attribute__((address_space(3))) unsigned int*)(l), 16, 0, 0)

__device__ __forceinline__ float bf2f(short s) {
  union { unsigned int u; float f; } x;
  x.u = ((unsigned int)(unsigned short)s) << 16;
  return x.f;
}

// ---------------- dtype sniff: cos[0]==1.0 exactly.
__global__ void sniff_k(const void* __restrict__ cosp, int* __restrict__ flag) {
  unsigned w = *(const unsigned*)cosp;
  *flag = (w == 0x3F800000u) ? 1 : 0;  // 1 = inputs are fp32
}

// ---------------- generic input -> bf16 convert, vectorized x8 ----------------
__global__ void conv_k(const void* __restrict__ src, bf16* __restrict__ dst, int n8,
                       const int* __restrict__ flag) {
  int i = blockIdx.x * blockDim.x + threadIdx.x;
  if (i >= n8) return;
  shortx8 r;
  if (*flag) {
    const float4* s4 = (const float4*)src;
    float4 x0 = s4[i * 2], x1 = s4[i * 2 + 1];
    float xs[8] = {x0.x, x0.y, x0.z, x0.w, x1.x, x1.y, x1.z, x1.w};
#pragma unroll
    for (int e = 0; e < 8; ++e)
      r[e] = (short)__bfloat16_as_ushort(__float2bfloat16(xs[e]));
  } else {
    r = ((const shortx8*)src)[i];
  }
  *(shortx8*)(dst + (size_t)i * 8) = r;
}

// ---------------- 6-way fused convert+transpose with output stride params ------------
// z: {wq, wk, wv, wo, cos, sin}. cos/sin interleave into ONE csT[d][2p] table
// (es=2, eo=0/1) so the gemm RoPE epilogue fetches cos+sin for 4 p's in one int4.
struct Trans6 {
  const void* src[6];
  bf16* dst[6];
  int C[6];    // source row width
  int rs[6];   // dst row stride (elements)
  int es[6];   // dst element stride
  int eo[6];   // dst element offset
};
__global__ void trans6_k(Trans6 td, const int* __restrict__ flag) {
  const int z = blockIdx.z;
  const int C = td.C[z];
  if ((int)blockIdx.x * 32 >= C) return;
  __shared__ bf16 tile[32][33];
  const void* src = td.src[z];
  bf16* dst = td.dst[z];
  const int rs = td.rs[z], es = td.es[z], eo = td.eo[z];
  int fp32 = *flag;
  int tx = threadIdx.x, ty = threadIdx.y;
  int c0 = blockIdx.x * 32, r0 = blockIdx.y * 32;
#pragma unroll
  for (int i = 0; i < 32; i += 8) {
    size_t idx = (size_t)(r0 + ty + i) * C + c0 + tx;
    tile[ty + i][tx] = fp32 ? __float2bfloat16(((const float*)src)[idx])
                            : ((const bf16*)src)[idx];
  }
  __syncthreads();
#pragma unroll
  for (int i = 0; i < 32; i += 8)
    dst[(size_t)(c0 + ty + i) * rs + (size_t)(r0 + tx) * es + eo] = tile[tx][ty + i];
}

// ---------------- GEMM BMx256, BK=64, conflict-free swizzle; EPI=1 fuses RoPE+Vt ------
// R8 post-mortem: BK=32 gemm was LDS-READ-pipe bound (MfmaUtil 23, VALUBusy 12) with a
// structural 4-way conflict: 64B rows have only 4 16B slots, 16 l15-lanes alias 4/slot.
// BK=64 gives 128B rows = 8 slots; slot ^= (row&7) (G4 fix) -> 2 lanes/slot = FREE
// (m136). Swizzle applied BOTH sides (rule #21): inverse on the per-lane GLOBAL source
// (DMA dest stays linear) and on ds_read addresses (row&7 == l15&7 for all frags).
// Ring-2 of K=64 tiles, TWO raw s_barriers per tile (same barrier rate as BK=32's one),
// counted vmcnt(GL) never draining mid-loop; stage(t+2) AFTER the read-complete
// barrier (overwrites buf t safely). T1 XCD swizzle (grids % 8 == 0).
template<int BM, int EPI>
__global__ __launch_bounds__(512) void gemm64(const bf16* __restrict__ A,
                                              const bf16* __restrict__ Bt,
                                              void* __restrict__ Cp,
                                              bf16* __restrict__ Vt,
                                              const bf16* __restrict__ csT,
                                              int M, int N, int K,
                                              const int* __restrict__ flag,
                                              int f32out_en) {
  constexpr int NR = BM / 32;            // row frags per wave: 8 or 4
  constexpr int ABASE = BM * 64;         // A K-tile shorts: 16384 or 8192
  constexpr int BUFS = ABASE + 16384;    // + B K-tile (256 x 64 shorts)
  __shared__ __align__(16) short lds[2][BUFS];
  const int f32out = (EPI == 0 && f32out_en) ? *flag : 0;
  const int tid = threadIdx.x;
  const int w = tid >> 6, lane = tid & 63;
  const int wr = w >> 2, wc = w & 3;
  const int quad = lane >> 4, l15 = lane & 15;

  // XCD-aware bijective swizzle (nwg % 8 == 0 for all launches)
  const int nwg = gridDim.x;
  const int id = blockIdx.x;
  const int swz = (id & 7) * (nwg >> 3) + (id >> 3);
  const int nbx = N >> 8;
  const int bx = swz % nbx, by = swz / nbx;
  const int m0 = by * BM, n0 = bx << 8;

  // staging source (inverse-swizzled): thread covers row rA (of each 64-row call
  // group), 16B slot (tid&7); global slot = (tid&7) ^ (row&7).  rA&7==(tid>>3)&7.
  const int rA = tid >> 3;               // 0..63
  const int sSrc = (((tid & 7) ^ (rA & 7)) << 3);
  const bf16* gA = A  + (size_t)(m0 + rA) * K + sSrc;
  const bf16* gB = Bt + (size_t)(n0 + rA) * K + sSrc;

  floatx4 acc[NR][4];
#pragma unroll
  for (int r = 0; r < NR; ++r)
#pragma unroll
    for (int c = 0; c < 4; ++c)
      acc[r][c] = (floatx4){0.f, 0.f, 0.f, 0.f};

  // ds_read offsets (shorts): slot = (ksub*4 + quad) ^ (row&7), row&7 == l15&7.
  const int sA0 = ((quad ^ (l15 & 7)) << 3);       // ksub 0
  const int sA1 = sA0 ^ 32;                        // ksub 1 (slot ^ 4)
  const int aBase = (wr * (BM / 2) + l15) * 64;
  const int bBase = ABASE + (wc * 64 + l15) * 64;

  const int nkt = K >> 6;

  auto STAGE = [&](int tt) {
    short* d_ = &lds[tt & 1][0];
    const int k0 = tt << 6;
    if constexpr (BM == 256) {
      GLOAD_LDS16(gA + k0,                     d_ + (w << 9));
      GLOAD_LDS16(gA + (size_t)64 * K + k0,    d_ + 4096 + (w << 9));
      GLOAD_LDS16(gA + (size_t)128 * K + k0,   d_ + 8192 + (w << 9));
      GLOAD_LDS16(gA + (size_t)192 * K + k0,   d_ + 12288 + (w << 9));
    } else {
      GLOAD_LDS16(gA + k0,                     d_ + (w << 9));
      GLOAD_LDS16(gA + (size_t)64 * K + k0,    d_ + 4096 + (w << 9));
    }
    GLOAD_LDS16(gB + k0,                       d_ + ABASE + (w << 9));
    GLOAD_LDS16(gB + (size_t)64 * K + k0,      d_ + ABASE + 4096 + (w << 9));
    GLOAD_LDS16(gB + (size_t)128 * K + k0,     d_ + ABASE + 8192 + (w << 9));
    GLOAD_LDS16(gB + (size_t)192 * K + k0,     d_ + ABASE + 12288 + (w << 9));
  };

  STAGE(0);
  STAGE(1);

  for (int t = 0; t < nkt; ++t) {
    // own tile-t loads complete; tile t+1's GL loads stay in flight (never drain)
    if (t + 1 < nkt) {
      if constexpr (BM == 256) asm volatile("s_waitcnt vmcnt(8)" ::: "memory");
      else                     asm volatile("s_waitcnt vmcnt(6)" ::: "memory");
    } else {
      asm volatile("s_waitcnt vmcnt(0)" ::: "memory");
    }
    __builtin_amdgcn_s_barrier();
    __builtin_amdgcn_sched_barrier(0);  // keep ds_reads below the barrier

    const short* bufS = &lds[t & 1][0];
#pragma unroll
    for (int ks = 0; ks < 2; ++ks) {
      const int sa = ks ? sA1 : sA0;
      bf16x8 af[NR], bfr[4];
#pragma unroll
      for (int r = 0; r < NR; ++r)
        af[r] = __builtin_bit_cast(bf16x8, *(const shortx8*)(bufS + aBase + r * 1024 + sa));
#pragma unroll
      for (int c = 0; c < 4; ++c)
        bfr[c] = __builtin_bit_cast(bf16x8, *(const shortx8*)(bufS + bBase + c * 1024 + sa));
#pragma unroll
      for (int r = 0; r < NR; ++r)
#pragma unroll
        for (int c = 0; c < 4; ++c)
          acc[r][c] = __builtin_amdgcn_mfma_f32_16x16x32_bf16(af[r], bfr[c], acc[r][c], 0, 0, 0);
    }
    __builtin_amdgcn_s_barrier();       // all waves done reading buf t
    __builtin_amdgcn_sched_barrier(0);
    if (t + 2 < nkt) STAGE(t + 2);      // overwrite buf t (safe: everyone passed barrier)
  }

  if constexpr (EPI == 1) {
    if (n0 >= 2560) {
      // ---- V columns: store transposed into Vt ----
#pragma unroll
      for (int r = 0; r < NR; ++r) {
#pragma unroll
        for (int c = 0; c < 4; ++c) {
          int dg = n0 + wc * 64 + c * 16 + l15 - 2560;   // 0..511
          int kvh = dg >> 6, dd = dg & 63;
          int mrow = m0 + wr * (BM / 2) + r * 16 + quad * 4;
          int bb = mrow >> 11, kv = mrow & 2047;
          shortx4 o4;
#pragma unroll
          for (int i = 0; i < 4; ++i)
            o4[i] = (short)__bfloat16_as_ushort(__float2bfloat16(acc[r][c][i]));
          *(shortx4*)(Vt + ((size_t)(bb * 8 + kvh) * 64 + dd) * 2048 + kv) = o4;
        }
      }
    } else {
      // ---- q/k columns: RoPE on fp32 acc; q also folds the exact 0.125 pre-scale ----
      const float qsc = (n0 < 2048) ? 0.125f : 1.0f;
#pragma unroll
      for (int r = 0; r < NR; ++r) {
        int mrow = m0 + wr * (BM / 2) + r * 16 + quad * 4;
        int pp = mrow & 2047;
#pragma unroll
        for (int c = 0; c < 4; ++c) {
          int ncol = n0 + wc * 64 + c * 16 + l15;
          int dd = ncol & 63;
          int4 cs4 = *(const int4*)(csT + (size_t)dd * 4096 + pp * 2);
          const short* sh = (const short*)&cs4;
          float sgn = (c & 2) ? 1.f : -1.f;  // d>=32: +sin*partner; d<32: -sin*partner
#pragma unroll
          for (int i = 0; i < 4; ++i) {
            float a = acc[r][c][i];
            float bp = acc[r][c ^ 2][i];
            float outv = (a * bf2f(sh[2 * i]) + sgn * bp * bf2f(sh[2 * i + 1])) * qsc;
            ((bf16*)Cp)[(size_t)(mrow + i) * 2560 + ncol] = __float2bfloat16(outv);
          }
        }
      }
    }
  } else {
#pragma unroll
    for (int r = 0; r < NR; ++r) {
#pragma unroll
      for (int c = 0; c < 4; ++c) {
        int mrow = m0 + wr * (BM / 2) + r * 16 + quad * 4;
        int ncol = n0 + wc * 64 + c * 16 + l15;
        if (f32out) {
#pragma unroll
          for (int i = 0; i < 4; ++i)
            ((float*)Cp)[(size_t)(mrow + i) * N + ncol] = acc[r][c][i];
        } else {
#pragma unroll
          for (int i = 0; i < 4; ++i)
            ((bf16*)Cp)[(size_t)(mrow + i) * N + ncol] = __float2bfloat16(acc[r][c][i]);
        }
      }
    }
  }
}

// ---------------- flash attention (causal, GQA 4:1) — swapped-QK^T, 64-row q-tiles ---
// Unchanged from R8 (passed, <84 us): 1024 uniform blocks (qt pair p / 31-p), 4
// blocks/CU; in-reg softmax; T13 defer-rescale; T5 setprio; Q pre-scaled in gemm.
__global__ __launch_bounds__(256) void attn_k(const bf16* __restrict__ qkv,
                                              const bf16* __restrict__ Vt,
                                              bf16* __restrict__ O) {
  const int S = 2048, LDQ = 2560, D = 2048;
  const int p = blockIdx.x, h = blockIdx.y, b = blockIdx.z;
  const int kvh = h >> 2;
  const int tid = threadIdx.x;
  const int w = tid >> 6, lane = tid & 63;
  const int quad = lane >> 4, l15 = lane & 15;

  __shared__ __align__(16) short sK [2][64][72];  // [buf][kv pos][hd]
  __shared__ __align__(16) short sVt[2][64][72];  // [buf][hd][kv pos]

  const int srow = tid >> 2, sseg = (tid & 3) * 16;
  const bf16* kbase = qkv + (size_t)(b * S) * LDQ + 2048 + kvh * 64 + sseg;       // row=kv
  const bf16* vbase = Vt + ((size_t)(b * 8 + kvh) * 64 + srow) * 2048 + sseg;     // row=d

  for (int phase = 0; phase < 2; ++phase) {
    const int qt = phase ? (31 - p) : p;
    const int q0 = qt * 64;

    bf16x8 qa[2];
    {
      const bf16* qp = qkv + (size_t)(b * S + q0 + w * 16 + l15) * LDQ + h * 64 + quad * 8;
      qa[0] = __builtin_bit_cast(bf16x8, *(const shortx8*)qp);
      qa[1] = __builtin_bit_cast(bf16x8, *(const shortx8*)(qp + 32));
    }

    floatx4 oacc[4];
#pragma unroll
    for (int d = 0; d < 4; ++d) oacc[d] = (floatx4){0.f, 0.f, 0.f, 0.f};
    float m_i = NEG_BIG, l_p = 0.f;

    const int jtEnd = qt + 1;

    {
      const bf16* kp = kbase + (size_t)srow * LDQ;
      *(int4*)&sK [0][srow][sseg]     = *(const int4*)kp;
      *(int4*)&sK [0][srow][sseg + 8] = *(const int4*)(kp + 8);
      *(int4*)&sVt[0][srow][sseg]     = *(const int4*)vbase;
      *(int4*)&sVt[0][srow][sseg + 8] = *(const int4*)(vbase + 8);
    }
    __syncthreads();

    int cur = 0;
    for (int jt = 0; jt < jtEnd; ++jt) {
      int4 kr0, kr1, vr0, vr1;
      const bool pre = (jt + 1 < jtEnd);
      if (pre) {
        const bf16* kp2 = kbase + (size_t)((jt + 1) * 64 + srow) * LDQ;
        kr0 = *(const int4*)kp2;
        kr1 = *(const int4*)(kp2 + 8);
        const bf16* vp2 = vbase + (jt + 1) * 64;
        vr0 = *(const int4*)vp2;
        vr1 = *(const int4*)(vp2 + 8);
      }

      floatx4 sfr[4];
#pragma unroll
      for (int nb = 0; nb < 4; ++nb) sfr[nb] = (floatx4){0.f, 0.f, 0.f, 0.f};
      __builtin_amdgcn_s_setprio(1);
#pragma unroll
      for (int kk = 0; kk < 2; ++kk) {
#pragma unroll
        for (int nb = 0; nb < 4; ++nb) {
          bf16x8 kf = __builtin_bit_cast(bf16x8,
              *(const shortx8*)&sK[cur][nb * 16 + l15][kk * 32 + quad * 8]);
          sfr[nb] = __builtin_amdgcn_mfma_f32_16x16x32_bf16(kf, qa[kk], sfr[nb], 0, 0, 0);
        }
      }
      __builtin_amdgcn_s_setprio(0);

      if (jt == qt) {
        const int rg = q0 + w * 16 + l15;
#pragma unroll
        for (int nb = 0; nb < 4; ++nb)
#pragma unroll
          for (int i = 0; i < 4; ++i) {
            int jg = jt * 64 + nb * 16 + quad * 4 + i;
            if (jg > rg) sfr[nb][i] = NEG_BIG;
          }
      }
      float m = fmaxf(fmaxf(sfr[0][0], sfr[0][1]), fmaxf(sfr[0][2], sfr[0][3]));
#pragma unroll
      for (int nb = 1; nb < 4; ++nb)
#pragma unroll
        for (int i = 0; i < 4; ++i) m = fmaxf(m, sfr[nb][i]);
      m = fmaxf(m, __shfl_xor(m, 16));
      m = fmaxf(m, __shfl_xor(m, 32));

      bool grow = m > m_i + 8.f;
      if (__any((int)grow)) {
        float Mn = fmaxf(m_i, m);
        float alpha = __expf(m_i - Mn);
        m_i = Mn;
        l_p *= alpha;
#pragma unroll
        for (int i = 0; i < 4; ++i) {
          float ai = __shfl(alpha, (lane & 48) | (quad * 4 + i));
#pragma unroll
          for (int d = 0; d < 4; ++d) oacc[d][i] *= ai;
        }
      }
      float rs = 0.f;
#pragma unroll
      for (int nb = 0; nb < 4; ++nb)
#pragma unroll
        for (int i = 0; i < 4; ++i) {
          float pv = __expf(sfr[nb][i] - m_i);
          sfr[nb][i] = pv;
          rs += pv;
        }
      l_p += rs;

      __builtin_amdgcn_s_setprio(1);
#pragma unroll
      for (int kk = 0; kk < 2; ++kk) {
        bf16x8 pf;
#pragma unroll
        for (int e = 0; e < 4; ++e) {
          pf[e]     = (__bf16)sfr[2 * kk][e];
          pf[e + 4] = (__bf16)sfr[2 * kk + 1][e];
        }
#pragma unroll
        for (int db = 0; db < 4; ++db) {
          const short* vrow = &sVt[cur][db * 16 + l15][0];
          shortx4 va = *(const shortx4*)(vrow + kk * 32 + quad * 4);
          shortx4 vb = *(const shortx4*)(vrow + kk * 32 + 16 + quad * 4);
          bf16x8 vf = __builtin_bit_cast(bf16x8,
              __builtin_shufflevector(va, vb, 0, 1, 2, 3, 4, 5, 6, 7));
          oacc[db] = __builtin_amdgcn_mfma_f32_16x16x32_bf16(pf, vf, oacc[db], 0, 0, 0);
        }
      }
      __builtin_amdgcn_s_setprio(0);

      if (pre) {
        *(int4*)&sK [cur ^ 1][srow][sseg]     = kr0;
        *(int4*)&sK [cur ^ 1][srow][sseg + 8] = kr1;
        *(int4*)&sVt[cur ^ 1][srow][sseg]     = vr0;
        *(int4*)&sVt[cur ^ 1][srow][sseg + 8] = vr1;
      }
      __syncthreads();
      cur ^= 1;
    }

    {
      float l = l_p;
      l += __shfl_xor(l, 16);
      l += __shfl_xor(l, 32);
      float inv = 1.f / l;
#pragma unroll
      for (int i = 0; i < 4; ++i) {
        float ii = __shfl(inv, (lane & 48) | (quad * 4 + i));
        bf16* op = O + (size_t)(b * S + q0 + w * 16 + quad * 4 + i) * D + h * 64 + l15;
#pragma unroll
        for (int db = 0; db < 4; ++db)
          op[db * 16] = __float2bfloat16(oacc[db][i] * ii);
      }
    }
  }
}

// ---------------- launch ----------------
// ws layout (bf16 elements from ws16 = d_ws + 16; flag int at d_ws):
//   xb 8.4M | csT 262k (interleaved cos/sin, [64][4096]) | bt_qkv 6.3M | wot 4.2M |
//   qkv(2560-wide) 10.5M | vt 2.1M  (~63.3 MB). o reuses xb.
// 6 launches: sniff, conv(x), trans6, gemmQKV(RoPE+Vt fused), attn, gemmOUT.
extern "C" void kernel_launch(void* const* d_in, const int* in_sizes, int n_in,
                              void* d_out, int out_size, void* d_ws, size_t ws_size,
                              hipStream_t stream) {
  const void* x    = d_in[0];
  const void* cosp = d_in[1];
  const void* sinp = d_in[2];
  const void* wq   = d_in[3];
  const void* wk   = d_in[4];
  const void* wv   = d_in[5];
  const void* wo   = d_in[6];

  int* flag = (int*)d_ws;
  bf16* ws16 = (bf16*)((char*)d_ws + 16);
  bf16* xb     = ws16;
  bf16* csT    = xb + (size_t)8388608;               // [64][4096] cos/sin interleaved
  bf16* bt_qkv = csT + 262144;
  bf16* wot    = bt_qkv + (size_t)3072 * 2048;
  bf16* qkv    = wot + (size_t)2048 * 2048;          // 4096 x 2560 (q+k only)
  bf16* vt     = qkv + (size_t)4096 * 2560;          // [2*8*64][2048]
  bf16* o      = xb;  // x dead after QKV GEMM; attn output reuses it

  sniff_k<<<1, 1, 0, stream>>>(cosp, flag);

  conv_k<<<(1048576 + 255) / 256, 256, 0, stream>>>(x, xb, 1048576, flag);

  Trans6 td;
  td.src[0] = wq;   td.dst[0] = bt_qkv;                       td.C[0] = 2048; td.rs[0] = 2048; td.es[0] = 1; td.eo[0] = 0;
  td.src[1] = wk;   td.dst[1] = bt_qkv + (size_t)2048 * 2048; td.C[1] = 512;  td.rs[1] = 2048; td.es[1] = 1; td.eo[1] = 0;
  td.src[2] = wv;   td.dst[2] = bt_qkv + (size_t)2560 * 2048; td.C[2] = 512;  td.rs[2] = 2048; td.es[2] = 1; td.eo[2] = 0;
  td.src[3] = wo;   td.dst[3] = wot;                          td.C[3] = 2048; td.rs[3] = 2048; td.es[3] = 1; td.eo[3] = 0;
  td.src[4] = cosp; td.dst[4] = csT;                          td.C[4] = 64;   td.rs[4] = 4096; td.es[4] = 2; td.eo[4] = 0;
  td.src[5] = sinp; td.dst[5] = csT;                          td.C[5] = 64;   td.rs[5] = 4096; td.es[5] = 2; td.eo[5] = 1;
  trans6_k<<<dim3(64, 64, 6), dim3(32, 8), 0, stream>>>(td, flag);

  // QKV projection + fused RoPE (q scaled 0.125) + fused V-transpose — BK=64 ring-2
  gemm64<256, 1><<<dim3(192), 512, 0, stream>>>(xb, bt_qkv, qkv, vt, csT,
                                                4096, 3072, 2048, flag, 0);

  // attention: 1024 uniform blocks (qt pair p / 31-p), 64-row q-tiles, 4 blocks/CU
  attn_k<<<dim3(16, 32, 2), 256, 0, stream>>>(qkv, vt, o);

  // output projection: BM=128, 256 blocks (100% util); dtype follows input
  gemm64<128, 0><<<dim3(256), 512, 0, stream>>>(o, wot, d_out, nullptr, nullptr,
                                                4096, 2048, 2048, flag, 1);
}